// Round 8
// baseline (126.182 us; speedup 1.0000x reference)
//
#include <hip/hip_runtime.h>
#include <math.h>

#define D_BINS 59
#define CO     64
#define CI     256
#define NB     4
#define NC     6
#define H_IMG  16
#define W_IMG  44
#define HW     704            // H_IMG * W_IMG
#define NPIX   (NB*NC*HW)     // 16896
#define XD     128
#define YD     128
#define ZD     7
#define NOUT   123            // D_BINS + CO
#define PXT    64             // pixels per k_head tile: 16896 = 264*64; 704 = 11*64
#define NTILE  264
#define XW     66             // X row width (64 cols + 2 pad)

typedef float v2f __attribute__((ext_vector_type(2)));

// ---------------------------------------------------------------------------
// Double-precision rigid-transform inverse (matches np.linalg.inv to ~1e-15,
// avoiding depth-bin boundary flips downstream).
// ---------------------------------------------------------------------------
__device__ void inv_rigid(const float* __restrict__ M, float* __restrict__ o) {
    double a = M[0], b = M[1], c = M[2], t0 = M[3];
    double d = M[4], e = M[5], f = M[6], t1 = M[7];
    double g = M[8], h = M[9], ii = M[10], t2 = M[11];
    double A00 = e*ii - f*h, A01 = c*h - b*ii, A02 = b*f - c*e;
    double A10 = f*g - d*ii, A11 = a*ii - c*g, A12 = c*d - a*f;
    double A20 = d*h - e*g,  A21 = b*g - a*h,  A22 = a*e - b*d;
    double det = a*A00 + b*A10 + c*A20;
    double inv = 1.0 / det;
    double r00 = A00*inv, r01 = A01*inv, r02 = A02*inv;
    double r10 = A10*inv, r11 = A11*inv, r12 = A12*inv;
    double r20 = A20*inv, r21 = A21*inv, r22 = A22*inv;
    o[0] = (float)r00; o[1] = (float)r01; o[2]  = (float)r02;
    o[3] = (float)(-(r00*t0 + r01*t1 + r02*t2));
    o[4] = (float)r10; o[5] = (float)r11; o[6]  = (float)r12;
    o[7] = (float)(-(r10*t0 + r11*t1 + r12*t2));
    o[8] = (float)r20; o[9] = (float)r21; o[10] = (float)r22;
    o[11] = (float)(-(r20*t0 + r21*t1 + r22*t2));
}

// ---------------------------------------------------------------------------
// Kernel 1: prep. W (123x256) -> wt2, k-pair-interleaved + transposed:
//   wt2[(k/2)*256 + o*2 + (k&1)], o zero-padded to 128. Unchanged.
// ---------------------------------------------------------------------------
__global__ __launch_bounds__(256) void k_pre(
    const float* __restrict__ wd, const float* __restrict__ c2e,
    float* __restrict__ wt2, float* __restrict__ e2c) {
    const int o = blockIdx.x;   // 0..127
    const int k = threadIdx.x;  // 0..255
    float v = (o < NOUT) ? wd[(size_t)o * CI + k] : 0.f;
    wt2[(size_t)(k >> 1) * 256 + o * 2 + (k & 1)] = v;
    if (blockIdx.x == 0 && k < NB * NC)
        inv_rigid(c2e + k * 16, e2c + k * 12);
}

// ---------------------------------------------------------------------------
// Kernel 2: depth/feat head. NEW this round: A IN REGISTERS.
// Diagnosis: 5 structures (s_load-W, LDS-W, global-A-per-k2, k-split,
// vector-W) all land at 38-46 us vs ~6 us VALU floor -> the invariant was
// the per-k2 A operand arriving through a memory pipe inside the FMA loop.
// Now: 64-px tiles (16896=264*64; 704=11*64 -> tile never crosses a camera,
// scalar bn, NO edge waves). Lane = pixel. Per kc chunk, each lane batch-
// loads its own pixel's 64 channels via 64 independent coalesced
// global_load_dword (64 outstanding/wave; in-order returns -> incremental
// vmcnt overlap into the FMAs). The k2 loop reads A from REGISTERS: no DS,
// no barriers in the main loop. W stays on the R4 scalar path (s_load).
// Grid (264,2) o-halves; half 0: logits+softmax+depth+feat0..4, half 1:
// feat5..63. LDS = X tile only (~17 KB). FMA order bit-identical to R4.
// ---------------------------------------------------------------------------
__global__ __launch_bounds__(256) void k_head(
    const float* __restrict__ img, const float* __restrict__ wt2,
    const float* __restrict__ bd, float* __restrict__ depth_out,
    float* __restrict__ feat_ws) {
    __shared__ float Xs[PXT * XW];           // 64 x 66
    __shared__ float S[PXT];

    const int tid = threadIdx.x;
    const int wv  = tid >> 6;                // 0..3 (all main)
    const int ln  = tid & 63;
    const int p0  = blockIdx.x * PXT;
    const int ob  = (int)blockIdx.y << 6;    // 0 or 64
    const int o0  = __builtin_amdgcn_readfirstlane(ob + (wv << 4));

    const int bn  = p0 / HW;                 // scalar: tile within one (b,n)
    const int hw0 = p0 - bn * HW;
    const float* base = img + (size_t)bn * CI * HW + hw0 + ln;

    v2f acc[16];
#pragma unroll
    for (int j = 0; j < 16; ++j) acc[j] = (v2f)(0.f);

    float a[64];                             // this lane's pixel: 64 channels
    for (int kc = 0; kc < 4; ++kc) {
#pragma unroll
        for (int c = 0; c < 64; ++c)         // 64 coalesced dwords, all in flight
            a[c] = base[(size_t)(kc * 64 + c) * HW];
#pragma unroll
        for (int k2 = 0; k2 < 32; ++k2) {
            v2f av = { a[2 * k2], a[2 * k2 + 1] };        // registers
            const v2f* w =
                (const v2f*)(wt2 + (size_t)(kc * 32 + k2) * 256) + o0;  // s_load
#pragma unroll
            for (int j = 0; j < 16; ++j)
                acc[j] = __builtin_elementwise_fma(av, w[j], acc[j]);
        }
    }

    // ---- epilogue into Xs[64][XW], col = o - ob (0..63) ----
#pragma unroll
    for (int j = 0; j < 16; ++j) {
        int o = o0 + j;
        if (o < NOUT)
            Xs[ln * XW + (o - ob)] = (acc[j].x + acc[j].y) + bd[o];
    }
    __syncthreads();

    if (blockIdx.y == 0) {
        // feat channels 0..4 (o = 59..63)
        for (int g = tid; g < PXT * 5; g += 256) {
            int p = g / 5, c = g - p * 5;
            feat_ws[(size_t)(p0 + p) * CO + c] = Xs[p * XW + 59 + c];
        }
        // softmax over cols 0..58, one thread per pixel
        if (tid < PXT) {
            float* row = Xs + tid * XW;
            float m = row[0];
            for (int o = 1; o < D_BINS; ++o) m = fmaxf(m, row[o]);
            float s = 0.f;
            for (int o = 0; o < D_BINS; ++o) {
                float e = __expf(row[o] - m);
                row[o] = e;
                s += e;
            }
            S[tid] = 1.f / s;
        }
        __syncthreads();
        // depth: tile region contiguous [p0*59, (p0+64)*59) -> coalesced
        for (int g = tid; g < PXT * D_BINS; g += 256) {
            int p = g / D_BINS;
            int o = g - p * D_BINS;
            depth_out[(size_t)p0 * D_BINS + g] = Xs[p * XW + o] * S[p];
        }
    } else {
        // feat channels 5..63 (o = 64..122 at cols 0..58)
        for (int g = tid; g < PXT * D_BINS; g += 256) {
            int p = g / D_BINS;
            int col = g - p * D_BINS;
            feat_ws[(size_t)(p0 + p) * CO + 5 + col] = Xs[p * XW + col];
        }
    }
}

// ---------------------------------------------------------------------------
// Kernel 3: project voxels, gather depth weight + feat, splat to BEV.
// Round-0 (124 us baseline) version, byte-identical.
// ---------------------------------------------------------------------------
__global__ __launch_bounds__(256) void k_splat(
    const float* __restrict__ e2c, const float* __restrict__ Kmat,
    const float* __restrict__ depth_g, const float* __restrict__ feat_ws,
    float* __restrict__ bev) {
    __shared__ int   hw_s[ZD][64];
    __shared__ float wgt_s[ZD][64];

    const int tx = threadIdx.x;          // 0..63 -> x
    const int cq = threadIdx.y;          // 0..3  -> channel quarter / z-slice
    const int x = blockIdx.x * 64 + tx;
    const int y = blockIdx.y;
    const int b = blockIdx.z;
    const float wx = (float)x * 0.8f + (-51.2f);
    const float wy = (float)y * 0.8f + (-51.2f);

    float acc[16];
#pragma unroll
    for (int m = 0; m < 16; ++m) acc[m] = 0.f;

    for (int n = 0; n < NC; ++n) {
        const int bn = b * NC + n;
        const float* E = e2c + bn * 12;
        const float* Km = Kmat + bn * 9;
        const float k00 = Km[0], k01 = Km[1], k02 = Km[2];
        const float k10 = Km[3], k11 = Km[4], k12 = Km[5];
        const float e02 = E[2], e12 = E[6], e22 = E[10];
        const float bx0 = E[0] * wx + E[1] * wy + E[3];
        const float bx1 = E[4] * wx + E[5] * wy + E[7];
        const float bx2 = E[8] * wx + E[9] * wy + E[11];

        // ---- projection phase: thread (tx,cq) owns z = cq and cq+4 ----
#pragma unroll
        for (int zz = 0; zz < 2; ++zz) {
            const int z = cq + zz * 4;
            if (z < ZD) {
                const float wz = -2.5f + (float)z;
                const float cx = bx0 + e02 * wz;
                const float cy = bx1 + e12 * wz;
                const float cz = bx2 + e22 * wz;
                const float zs = fmaxf(cz, 0.1f);
                const float rz = 1.0f / zs;         // IEEE divide
                const float xn = cx * rz;
                const float yn = cy * rz;
                const float fu = (k00 * xn + k01 * yn + k02) * 0.0625f;
                const float fv = (k10 * xn + k11 * yn + k12) * 0.0625f;
                const int bin = (int)(cz - 1.0f);   // trunc, matches astype(int32)
                const bool valid = (fu >= 0.f) & (fu < (float)W_IMG) &
                                   (fv >= 0.f) & (fv < (float)H_IMG) &
                                   (cz > 0.5f) & (bin >= 0) & (bin < D_BINS);
                int hw = -1;
                float wgt = 0.f;
                if (valid) {
                    int u = (int)fu;                // valid => in range
                    int v = (int)fv;
                    hw = v * W_IMG + u;
                    wgt = depth_g[((size_t)bn * HW + hw) * D_BINS + bin];
                }
                hw_s[z][tx] = hw;
                wgt_s[z][tx] = wgt;
            }
        }
        __syncthreads();

        // ---- accumulate phase: z ascending (same FMA order as baseline) ----
#pragma unroll
        for (int z = 0; z < ZD; ++z) {
            const int hw = hw_s[z][tx];       // 4 cq threads same addr: broadcast
            if (hw >= 0) {
                const float wgt = wgt_s[z][tx];
                const float4* fp =
                    (const float4*)(feat_ws + ((size_t)bn * HW + hw) * CO + cq * 16);
                float4 f0 = fp[0], f1 = fp[1], f2 = fp[2], f3 = fp[3];
                acc[0]  = fmaf(wgt, f0.x, acc[0]);
                acc[1]  = fmaf(wgt, f0.y, acc[1]);
                acc[2]  = fmaf(wgt, f0.z, acc[2]);
                acc[3]  = fmaf(wgt, f0.w, acc[3]);
                acc[4]  = fmaf(wgt, f1.x, acc[4]);
                acc[5]  = fmaf(wgt, f1.y, acc[5]);
                acc[6]  = fmaf(wgt, f1.z, acc[6]);
                acc[7]  = fmaf(wgt, f1.w, acc[7]);
                acc[8]  = fmaf(wgt, f2.x, acc[8]);
                acc[9]  = fmaf(wgt, f2.y, acc[9]);
                acc[10] = fmaf(wgt, f2.z, acc[10]);
                acc[11] = fmaf(wgt, f2.w, acc[11]);
                acc[12] = fmaf(wgt, f3.x, acc[12]);
                acc[13] = fmaf(wgt, f3.y, acc[13]);
                acc[14] = fmaf(wgt, f3.z, acc[14]);
                acc[15] = fmaf(wgt, f3.w, acc[15]);
            }
        }
        __syncthreads();   // LDS reused next n
    }
    // out[b][c][y][x], c = cq*16 + m; 64 lanes = consecutive x -> coalesced
    float* ob = bev + (((size_t)b * CO + cq * 16) * YD + y) * XD + x;
#pragma unroll
    for (int m = 0; m < 16; ++m) ob[(size_t)m * YD * XD] = acc[m];
}

extern "C" void kernel_launch(void* const* d_in, const int* in_sizes, int n_in,
                              void* d_out, int out_size, void* d_ws, size_t ws_size,
                              hipStream_t stream) {
    const float* img  = (const float*)d_in[0];  // (B,N,256,16,44)
    const float* c2e  = (const float*)d_in[1];  // (B,N,4,4)
    const float* Kmat = (const float*)d_in[2];  // (B,N,3,3)
    const float* wd   = (const float*)d_in[3];  // (123,256)
    const float* bd   = (const float*)d_in[4];  // (123,)
    float* bev = (float*)d_out;                         // (B,64,128,128)
    float* depth_out = bev + (size_t)NB * CO * YD * XD; // (B,N,16,44,59)
    float* feat_ws = (float*)d_ws;                      // NPIX*64 floats
    float* wt2 = feat_ws + (size_t)NPIX * CO;           // 128*256 floats
    float* e2c = wt2 + 128 * 256;                       // 24*12 floats

    k_pre<<<128, 256, 0, stream>>>(wd, c2e, wt2, e2c);
    k_head<<<dim3(NTILE, 2), 256, 0, stream>>>(img, wt2, bd, depth_out, feat_ws);
    k_splat<<<dim3(2, YD, NB), dim3(64, 4, 1), 0, stream>>>(e2c, Kmat, depth_out,
                                                            feat_ws, bev);
}